// Round 13
// baseline (4801.727 us; speedup 1.0000x reference)
//
#include <hip/hip_runtime.h>
#include <math.h>

// ---------------------------------------------------------------------------
// Bidirectional 2-layer LSTM (S=1024, B=64, IN=128, H=256) + linear head.
// Round 13: r12 verbatim + ONE structural delta in the rec loop:
//   __syncthreads() (= vmcnt(0)+lgkmcnt(0)+barrier) -> lgkmcnt(0)+s_barrier.
//   LDS-only ordering is sufficient for the hls double buffer; y-stores and
//   zx-loads may now stay in flight ACROSS the barrier. With the drain gone,
//   one-step zq prefetch actually hides the ~900cyc HBM latency (r9's version
//   could not: the vmcnt(0) drain forced prefetched loads to complete at the
//   barrier). Unconditional prefetch is in-buffer at both chunk ends.
// ---------------------------------------------------------------------------

typedef float f4 __attribute__((ext_vector_type(4)));
typedef float f32x4 __attribute__((ext_vector_type(4)));
typedef int i32x4 __attribute__((ext_vector_type(4)));
typedef short bf16x8 __attribute__((ext_vector_type(8)));
typedef unsigned short u16;
typedef unsigned short u16x4 __attribute__((ext_vector_type(4)));

#define S_LEN 1024

__device__ __forceinline__ float rcpf(float x) {
  return __builtin_amdgcn_rcpf(x);
}
__device__ __forceinline__ float fsig(float x) {
  return rcpf(1.0f + __expf(-x));            // v_exp + v_add + v_rcp
}
__device__ __forceinline__ float ftanh(float x) {
  // tanh(x) = 1 - 2/(1+exp(2x))
  return fmaf(-2.0f, rcpf(1.0f + __expf(2.0f * x)), 1.0f);
}

__device__ __forceinline__ float b2f_raw(u16 u) {
  union { unsigned u; float f; } c;
  c.u = ((unsigned)u) << 16;
  return c.f;
}
__device__ __forceinline__ u16 f2b_raw(float f) {
  union { float f; unsigned u; } c;
  c.f = f;
  unsigned r = c.u + 0x7FFFu + ((c.u >> 16) & 1u);  // RNE
  return (u16)(r >> 16);
}

__device__ __forceinline__ f4 ld4(const float* p) { return *(const f4*)p; }
__device__ __forceinline__ f4 ld4(const u16* p) {
  u16x4 q = *(const u16x4*)p;
  f4 r;
  r[0] = b2f_raw(q[0]); r[1] = b2f_raw(q[1]);
  r[2] = b2f_raw(q[2]); r[3] = b2f_raw(q[3]);
  return r;
}
__device__ __forceinline__ void st4(float* p, f4 v) { *(f4*)p = v; }
__device__ __forceinline__ void st4(u16* p, f4 v) {
  u16x4 q;
  q[0] = f2b_raw(v[0]); q[1] = f2b_raw(v[1]);
  q[2] = f2b_raw(v[2]); q[3] = f2b_raw(v[3]);
  *(u16x4*)p = q;
}

__device__ __forceinline__ bf16x8 cvt_bf8(f4 a, f4 b) {
  bf16x8 r;
#pragma unroll
  for (int e = 0; e < 4; ++e) {
    r[e] = (short)f2b_raw(a[e]);
    r[4 + e] = (short)f2b_raw(b[e]);
  }
  return r;
}

// byte-address swizzle for 256B-row i8 LDS tiles (row bits 8-10 -> slot bits 4-6)
__device__ __forceinline__ int swz8(int byte) {
  return byte ^ (((byte >> 8) & 7) << 4);
}

// LDS-only barrier: order ds ops, let vmem (y stores, zx loads) fly across.
__device__ __forceinline__ void lds_barrier() {
  asm volatile("s_waitcnt lgkmcnt(0)" ::: "memory");
  __builtin_amdgcn_s_barrier();
}

// ---------------------------------------------------------------------------
__global__ void fill_val(float* o, float v, unsigned n) {
  unsigned i = blockIdx.x * 256u + threadIdx.x;
  if (i < n) o[i] = v;
}

// Per-column int8 quantization of W_hh: wq[col][k], wsc[col] = s/(127*127).
__global__ __launch_bounds__(256) void cvt_w_i8(const float* __restrict__ src,
                                                signed char* __restrict__ wq,
                                                float* __restrict__ wsc) {
  const int col = blockIdx.x * 4 + (threadIdx.x >> 6);
  const int lane = threadIdx.x & 63;
  const float* sp = src + (size_t)col * 256 + lane * 4;
  f4 v = *(const f4*)sp;
  float m = fmaxf(fmaxf(fabsf(v[0]), fabsf(v[1])),
                  fmaxf(fabsf(v[2]), fabsf(v[3])));
#pragma unroll
  for (int off = 32; off; off >>= 1) m = fmaxf(m, __shfl_xor(m, off));
  m = fmaxf(m, 1e-20f);
  const float r = 127.0f / m;
  signed char qb[4];
#pragma unroll
  for (int e = 0; e < 4; ++e) qb[e] = (signed char)__float2int_rn(v[e] * r);
  *(int*)(wq + (size_t)col * 256 + lane * 4) = *(int*)qb;
  if (lane == 0) wsc[col] = m / (127.0f * 127.0f);
}

// ---------------------------------------------------------------------------
// bf16 MFMA zx-GEMM body (r11 verbatim). Block gb covers a 64x256 tile of one
// dir's [CT*64 x 1024] zx chunk. 16 waves: wave w -> rows (w&3)*16, cols
// (w>>2)*64. Writes dense zx layout ((dd*CT+t)*4+bg)*16384 + col*16 + bi.
// ---------------------------------------------------------------------------
template <int CT, int LAYER>
__device__ __forceinline__ void zx_gemm_body(
    int gb, int tid, u16* __restrict__ zx_nxt, const float* __restrict__ xsrc,
    const u16* __restrict__ ysrc, const float* __restrict__ wih,
    const float* __restrict__ bih, const float* __restrict__ bhh, int t0dF,
    int t0dR) {
  const int dd = gb / (4 * CT);
  const int rr = gb % (4 * CT);
  const int mblk = rr >> 2;  // t-step within chunk
  const int nblk = rr & 3;   // 256-col group
  const int w = tid >> 6, l = tid & 63;
  const int c = l & 15, q = l >> 4;
  const int mt = w & 3;      // 16-row tile (= bg)
  const int ct4 = w >> 2;    // 64-col strip
  const int K = LAYER ? 512 : 128;
  const int tg = (dd ? t0dR : t0dF) + mblk;
  const int bb = mt * 16 + c;  // A row (batch within 64)
  const int n0 = nblk * 256 + ct4 * 64;

  const float* wB = wih + (size_t)dd * 1024 * K;

  f32x4 acc[4];
#pragma unroll
  for (int j = 0; j < 4; ++j) acc[j] = (f32x4){0.f, 0.f, 0.f, 0.f};

  for (int k0 = 0; k0 < K; k0 += 32) {
    bf16x8 afrag;
    if (LAYER == 0) {
      const float* ap =
          xsrc + (size_t)bb * (1024 * 128) + (size_t)tg * 128 + k0 + q * 8;
      afrag = cvt_bf8(*(const f4*)ap, *(const f4*)(ap + 4));
    } else {
      afrag =
          *(const bf16x8*)(ysrc + ((size_t)tg * 64 + bb) * 512 + k0 + q * 8);
    }
#pragma unroll
    for (int j = 0; j < 4; ++j) {
      const int col = n0 + j * 16 + c;
      const float* bp = wB + (size_t)col * K + k0 + q * 8;
      bf16x8 bfrag = cvt_bf8(*(const f4*)bp, *(const f4*)(bp + 4));
      acc[j] = __builtin_amdgcn_mfma_f32_16x16x32_bf16(afrag, bfrag, acc[j],
                                                       0, 0, 0);
    }
  }
  // D row=q*4+i -> b = mt*16 + q*4+i -> bg=mt, bi=q*4+i (u16x4 store)
  u16* base = zx_nxt + ((size_t)(dd * CT + mblk) * 4 + mt) * 16384;
#pragma unroll
  for (int j = 0; j < 4; ++j) {
    const int col = n0 + j * 16 + c;
    const float bvv = bih[dd * 1024 + col] + bhh[dd * 1024 + col];
    u16x4 o;
#pragma unroll
    for (int i = 0; i < 4; ++i) o[i] = f2b_raw(acc[j][i] + bvv);
    *(u16x4*)(base + (size_t)col * 16 + q * 4) = o;
  }
}

// Standalone prologue version.
template <int CT, int LAYER>
__global__ __launch_bounds__(1024) void gemm_zx(
    u16* __restrict__ zx_dst, const float* __restrict__ xsrc,
    const u16* __restrict__ ysrc, const float* __restrict__ wih,
    const float* __restrict__ bih, const float* __restrict__ bhh, int t0dF,
    int t0dR) {
  zx_gemm_body<CT, LAYER>(blockIdx.x, threadIdx.x, zx_dst, xsrc, ysrc, wih,
                          bih, bhh, t0dF, t0dR);
}

// ---------------------------------------------------------------------------
// Head GEMM (f32): out = y1 @ lin_w^T + b.
// ---------------------------------------------------------------------------
__global__ __launch_bounds__(256) void gemm_head(
    const u16* __restrict__ A, const float* __restrict__ Bw,
    const float* __restrict__ bias1, float* __restrict__ C, int K, int N) {
  const int tid = threadIdx.x;
  const int nt = blockIdx.x, mt = blockIdx.y;
  const int tx = tid & 15, ty = tid >> 4;

  __shared__ float As[32 * 64];
  __shared__ float Bs[32 * 64];

  f4 zero = {0.f, 0.f, 0.f, 0.f};
  f4 acc[4] = {zero, zero, zero, zero};

  const int am = tid & 63, akq = tid >> 6;
  const long abase = (long)am * K + (long)mt * 64 * K;

  for (int kt = 0; kt < K; kt += 32) {
    {
      const u16* ap = A + abase + kt + akq * 8;
      f4 v0 = ld4(ap);
      f4 v1 = ld4(ap + 4);
#pragma unroll
      for (int e = 0; e < 4; ++e) {
        As[(akq * 8 + e) * 64 + am] = v0[e];
        As[(akq * 8 + 4 + e) * 64 + am] = v1[e];
      }
      const float* bp = Bw + (size_t)((nt * 64 + am) & 63) * K + kt + akq * 8;
      f4 w0 = *(const f4*)bp;
      f4 w1 = *(const f4*)(bp + 4);
#pragma unroll
      for (int e = 0; e < 4; ++e) {
        Bs[(akq * 8 + e) * 64 + am] = w0[e];
        Bs[(akq * 8 + 4 + e) * 64 + am] = w1[e];
      }
    }
    __syncthreads();
#pragma unroll 8
    for (int k = 0; k < 32; ++k) {
      f4 a = *(const f4*)(As + k * 64 + ty * 4);
      f4 b = *(const f4*)(Bs + k * 64 + tx * 4);
      acc[0] += b * a[0];
      acc[1] += b * a[1];
      acc[2] += b * a[2];
      acc[3] += b * a[3];
    }
    __syncthreads();
  }
  f4 bv = *(const f4*)(bias1 + nt * 64 + tx * 4);
  float* Cp = C + ((size_t)mt * 64 + ty * 4) * N + nt * 64 + tx * 4;
#pragma unroll
  for (int i = 0; i < 4; ++i) st4(Cp + (size_t)i * N, acc[i] + bv);
}

// ---------------------------------------------------------------------------
// Fused kernel: blocks 0-7 = int8 MFMA recurrence; blocks 8.. = bf16 MFMA
// zx GEMM for NEXT chunk. Rec loop uses LDS-only barrier + 1-step zq prefetch.
// ---------------------------------------------------------------------------
template <int CT, int LAYER>
__global__ __launch_bounds__(1024) void rec_fused(
    const u16* __restrict__ zx_cur, u16* __restrict__ zx_nxt,
    const float* __restrict__ xsrc, const u16* __restrict__ ysrc,
    const float* __restrict__ wih, const float* __restrict__ bih,
    const float* __restrict__ bhh, const signed char* __restrict__ wq,
    const float* __restrict__ wsc, const float* __restrict__ h0,
    const float* __restrict__ c0, int l2, float* __restrict__ cstate,
    u16* __restrict__ y, int t0, int t0dF, int t0dR, int do_gemm) {
  __shared__ alignas(16) char hls[2 * 4096];
  __shared__ float sred[8];

  const int tid = threadIdx.x;

  if (blockIdx.x >= 8) {
    if (!do_gemm) return;
    zx_gemm_body<CT, LAYER>((int)blockIdx.x - 8, tid, zx_nxt, xsrc, ysrc, wih,
                            bih, bhh, t0dF, t0dR);
    return;
  }

  // ================= REC part (blocks 0-7) =================
  const int w = tid >> 6, l = tid & 63;
  const int c = l & 15, q = l >> 4;
  const int d = blockIdx.x >> 2, bg = blockIdx.x & 3;
  const int u0 = w * 16, b0 = bg * 16;
  const int sidx = l2 + d;

  // resident W_hh fragments + scales (64 VGPR)
  i32x4 wf[4][4];
  float sc[4];
  {
    const signed char* wd = wq + (size_t)d * 1024 * 256;
#pragma unroll
    for (int g = 0; g < 4; ++g) {
      const int col = g * 256 + u0 + c;
      sc[g] = wsc[d * 1024 + col];
#pragma unroll
      for (int kt = 0; kt < 4; ++kt)
        wf[kt][g] = *(const i32x4*)(wd + (size_t)col * 256 + kt * 64 + q * 16);
    }
  }

  // h init (first 512 threads; barrier hoisted)
  float hv8[8];
  const int hb = tid >> 5, hg = tid & 31;
  if (tid < 512) {
    if (t0 == 0) {
      const float* hp = h0 + ((size_t)sidx * 64 + b0 + hb) * 256 + hg * 8;
      f4 v0 = ld4(hp), v1 = ld4(hp + 4);
#pragma unroll
      for (int e = 0; e < 4; ++e) { hv8[e] = v0[e]; hv8[4 + e] = v1[e]; }
    } else {
      const int r0 = d ? (S_LEN - t0) : (t0 - 1);
      const u16* hp = y + ((size_t)r0 * 64 + b0 + hb) * 512 + d * 256 + hg * 8;
      f4 v0 = ld4(hp), v1 = ld4(hp + 4);
#pragma unroll
      for (int e = 0; e < 4; ++e) { hv8[e] = v0[e]; hv8[4 + e] = v1[e]; }
    }
    float m = 0.f;
#pragma unroll
    for (int e = 0; e < 8; ++e) m = fmaxf(m, fabsf(hv8[e]));
#pragma unroll
    for (int off = 32; off; off >>= 1) m = fmaxf(m, __shfl_xor(m, off));
    if (l == 0) sred[w] = m;
  }
  __syncthreads();
  float s_h0;
  {
    float m = 1e-20f;
#pragma unroll
    for (int i = 0; i < 8; ++i) m = fmaxf(m, sred[i]);
    s_h0 = m;
  }
  if (tid < 512) {
    const float r = 127.0f / s_h0;
#pragma unroll
    for (int e = 0; e < 8; ++e) {
      hls[swz8(hb * 256 + hg * 8 + e)] =
          (signed char)__float2int_rn(hv8[e] * r);
    }
  }

  // c state
  float cst[4];
  if (t0 == 0) {
#pragma unroll
    for (int i = 0; i < 4; ++i)
      cst[i] = c0[((size_t)sidx * 64 + b0 + q * 4 + i) * 256 + u0 + c];
  } else {
    const float* cp = cstate + ((size_t)blockIdx.x * 1024 + tid) * 4;
#pragma unroll
    for (int i = 0; i < 4; ++i) cst[i] = cp[i];
  }
  __syncthreads();

  // incremental pointers (dense zx layout)
  const u16* zp =
      zx_cur + ((size_t)(d * CT + (d ? CT - 1 : 0)) * 4 + bg) * 16384;
  const long zstep = d ? -65536L : 65536L;
  int zo[4];
#pragma unroll
  for (int g = 0; g < 4; ++g) zo[g] = g * 4096 + (u0 + c) * 16 + q * 4;
  u16* yp = y + ((size_t)(d ? (S_LEN - 1 - t0) : t0) * 64 + b0) * 512 +
            d * 256 + u0 + c;
  const long ystep = d ? -32768L : 32768L;

  // first step's zq (in flight during h-init epilogue)
  u16x4 zq[4];
#pragma unroll
  for (int g = 0; g < 4; ++g) zq[g] = *(const u16x4*)(zp + zo[g]);

  float s_cur = s_h0;
  for (int tl = 0; tl < CT; ++tl) {
    const int curo = (tl & 1) * 4096, nxto = 4096 - curo;

    // issue NEXT step's zx loads; they stay in flight across the raw barrier.
    // Unconditional: one-past-end stays inside the zx allocation (other dir's
    // region) for both d=0 and d=1.
    const u16* zpn = zp + zstep;
    u16x4 zqn[4];
#pragma unroll
    for (int g = 0; g < 4; ++g) zqn[g] = *(const u16x4*)(zpn + zo[g]);

    // h @ W_hh^T : 4 k-tiles (K=64) x 4 gate-tiles, B resident
    i32x4 acc[4];
#pragma unroll
    for (int g = 0; g < 4; ++g) acc[g] = (i32x4){0, 0, 0, 0};
#pragma unroll
    for (int kt = 0; kt < 4; ++kt) {
      i32x4 af = *(const i32x4*)(hls + curo + swz8(c * 256 + kt * 64 + q * 16));
#pragma unroll
      for (int g = 0; g < 4; ++g)
        acc[g] = __builtin_amdgcn_mfma_i32_16x16x64_i8(af, wf[kt][g],
                                                       acc[g], 0, 0, 0);
    }

    // gates + state update: 4 outputs/lane (b=q*4+i, u=u0+c)
    const float sI = sc[0] * s_cur, sF = sc[1] * s_cur;
    const float sG = sc[2] * s_cur, sO = sc[3] * s_cur;
#pragma unroll
    for (int i = 0; i < 4; ++i) {
      const float zI = b2f_raw(zq[0][i]) + sI * (float)acc[0][i];
      const float zF = b2f_raw(zq[1][i]) + sF * (float)acc[1][i];
      const float zG = b2f_raw(zq[2][i]) + sG * (float)acc[2][i];
      const float zO = b2f_raw(zq[3][i]) + sO * (float)acc[3][i];
      const float cv = fsig(zF) * cst[i] + fsig(zI) * ftanh(zG);
      cst[i] = cv;
      const float hv = fsig(zO) * ftanh(cv);
      const int b = q * 4 + i;
      hls[nxto + swz8(b * 256 + u0 + c)] =
          (signed char)__float2int_rn(hv * 127.0f);
      yp[(size_t)b * 512] = f2b_raw(hv);
    }
    s_cur = 1.0f;
#pragma unroll
    for (int g = 0; g < 4; ++g) zq[g] = zqn[g];
    zp = zpn;
    yp += ystep;
    // LDS-only barrier: ds ops ordered; y-stores/zx-loads fly across.
    lds_barrier();
  }

  {
    float* cp = cstate + ((size_t)blockIdx.x * 1024 + tid) * 4;
#pragma unroll
    for (int i = 0; i < 4; ++i) cp[i] = cst[i];
  }
}

// ---------------------------------------------------------------------------
struct Args {
  const float *x, *h0, *c0, *wih0, *whh0, *bih0, *bhh0, *wih1, *whh1, *bih1,
      *bhh1, *linw, *linb;
  float* out;
  u16 *y0, *y1, *zxA, *zxB;
  signed char* wq;
  float *wsc, *cstate;
};

template <int CTT>
static void run_pipeline(const Args& a, hipStream_t stream) {
  const int nC = S_LEN / CTT;
  const int NG = 8 * CTT;
  for (int L = 0; L < 2; ++L) {
    cvt_w_i8<<<dim3(512), 256, 0, stream>>>(L ? a.whh1 : a.whh0, a.wq, a.wsc);
    // chunk-0 prologue gemm (both dirs inside one launch) -> zxA
    if (L == 0) {
      gemm_zx<CTT, 0><<<dim3(NG), 1024, 0, stream>>>(
          a.zxA, a.x, nullptr, a.wih0, a.bih0, a.bhh0, 0, S_LEN - CTT);
    } else {
      gemm_zx<CTT, 1><<<dim3(NG), 1024, 0, stream>>>(
          a.zxA, nullptr, a.y0, a.wih1, a.bih1, a.bhh1, 0, S_LEN - CTT);
    }
    u16* yl = L ? a.y1 : a.y0;
    for (int ch = 0; ch < nC; ++ch) {
      u16* zc = (ch & 1) ? a.zxB : a.zxA;
      u16* zn = (ch & 1) ? a.zxA : a.zxB;
      const int t0dF = (ch + 1) * CTT;
      const int t0dR = S_LEN - (ch + 2) * CTT;
      const int dg = (ch + 1 < nC) ? 1 : 0;
      if (L == 0) {
        rec_fused<CTT, 0><<<dim3(8 + NG), 1024, 0, stream>>>(
            zc, zn, a.x, nullptr, a.wih0, a.bih0, a.bhh0, a.wq, a.wsc, a.h0,
            a.c0, 0, a.cstate, yl, ch * CTT, t0dF, t0dR, dg);
      } else {
        rec_fused<CTT, 1><<<dim3(8 + NG), 1024, 0, stream>>>(
            zc, zn, nullptr, a.y0, a.wih1, a.bih1, a.bhh1, a.wq, a.wsc, a.h0,
            a.c0, 2, a.cstate, yl, ch * CTT, t0dF, t0dR, dg);
      }
    }
  }
  // head: out = y1 @ lin_w^T + lin_b
  gemm_head<<<dim3(1, 1024, 1), 256, 0, stream>>>(a.y1, a.linw, a.linb, a.out,
                                                  512, 64);
}

// ---------------------------------------------------------------------------
extern "C" void kernel_launch(void* const* d_in, const int* in_sizes, int n_in,
                              void* d_out, int out_size, void* d_ws,
                              size_t ws_size, hipStream_t stream) {
  Args a;
  a.x    = (const float*)d_in[0];
  a.h0   = (const float*)d_in[1];
  a.c0   = (const float*)d_in[2];
  a.wih0 = (const float*)d_in[3];
  a.whh0 = (const float*)d_in[4];
  a.bih0 = (const float*)d_in[5];
  a.bhh0 = (const float*)d_in[6];
  a.wih1 = (const float*)d_in[7];
  a.whh1 = (const float*)d_in[8];
  a.bih1 = (const float*)d_in[9];
  a.bhh1 = (const float*)d_in[10];
  a.linw = (const float*)d_in[11];
  a.linb = (const float*)d_in[12];
  a.out  = (float*)d_out;

  const size_t Yb  = (size_t)S_LEN * 64 * 512 * 2;  // 64 MB each
  const size_t WQb = 2UL * 1024 * 256;              // 512 KB
  const size_t WSb = 2UL * 1024 * 4;                // 8 KB
  const size_t CSb = 8UL * 1024 * 4 * 4;            // 128 KB
  const size_t fixed = 2 * Yb + WQb + WSb + CSb;

  int CT = 0;
  const int cands[6] = {256, 128, 64, 32, 16, 8};
  for (int ci = 0; ci < 6; ++ci) {
    const size_t zxb = (size_t)cands[ci] * 262144;  // bytes per buffer
    if (fixed + 2 * zxb <= ws_size) { CT = cands[ci]; break; }
  }
  if (CT == 0) {  // diagnostic: absmax == ws MB
    fill_val<<<dim3(((unsigned)out_size + 255u) / 256u), 256, 0, stream>>>(
        a.out, (float)(unsigned)(ws_size >> 20), (unsigned)out_size);
    return;
  }

  char* wsp = (char*)d_ws;
  a.y0     = (u16*)wsp;
  a.y1     = (u16*)(wsp + Yb);
  a.wq     = (signed char*)(wsp + 2 * Yb);
  a.wsc    = (float*)(wsp + 2 * Yb + WQb);
  a.cstate = (float*)(wsp + 2 * Yb + WQb + WSb);
  a.zxA    = (u16*)(wsp + fixed);
  a.zxB    = (u16*)(wsp + fixed + (size_t)CT * 262144);

  switch (CT) {
    case 256: run_pipeline<256>(a, stream); break;
    case 128: run_pipeline<128>(a, stream); break;
    case 64:  run_pipeline<64>(a, stream); break;
    case 32:  run_pipeline<32>(a, stream); break;
    case 16:  run_pipeline<16>(a, stream); break;
    default:  run_pipeline<8>(a, stream); break;
  }
}

// Round 14
// 4119.488 us; speedup vs baseline: 1.1656x; 1.1656x over previous
//
#include <hip/hip_runtime.h>
#include <math.h>

// ---------------------------------------------------------------------------
// Bidirectional 2-layer LSTM (S=1024, B=64, IN=128, H=256) + linear head.
// Round 14: r13 + two contention fixes:
//   (1) rec waves run at s_setprio(1); co-resident gemm waves (prio 0) only
//       fill idle issue slots on the 8 critical CUs.
//   (2) W_ih pre-converted to bf16 once per layer -> gemm B-frags are direct
//       loads (deletes ~80 VALU/k-step from the contention source).
//       Rounding identical to the old in-register cvt => bit-identical zx.
// ---------------------------------------------------------------------------

typedef float f4 __attribute__((ext_vector_type(4)));
typedef float f32x4 __attribute__((ext_vector_type(4)));
typedef int i32x4 __attribute__((ext_vector_type(4)));
typedef short bf16x8 __attribute__((ext_vector_type(8)));
typedef unsigned short u16;
typedef unsigned short u16x4 __attribute__((ext_vector_type(4)));

#define S_LEN 1024

__device__ __forceinline__ float rcpf(float x) {
  return __builtin_amdgcn_rcpf(x);
}
__device__ __forceinline__ float fsig(float x) {
  return rcpf(1.0f + __expf(-x));
}
__device__ __forceinline__ float ftanh(float x) {
  return fmaf(-2.0f, rcpf(1.0f + __expf(2.0f * x)), 1.0f);
}

__device__ __forceinline__ float b2f_raw(u16 u) {
  union { unsigned u; float f; } c;
  c.u = ((unsigned)u) << 16;
  return c.f;
}
__device__ __forceinline__ u16 f2b_raw(float f) {
  union { float f; unsigned u; } c;
  c.f = f;
  unsigned r = c.u + 0x7FFFu + ((c.u >> 16) & 1u);  // RNE
  return (u16)(r >> 16);
}

__device__ __forceinline__ f4 ld4(const float* p) { return *(const f4*)p; }
__device__ __forceinline__ f4 ld4(const u16* p) {
  u16x4 q = *(const u16x4*)p;
  f4 r;
  r[0] = b2f_raw(q[0]); r[1] = b2f_raw(q[1]);
  r[2] = b2f_raw(q[2]); r[3] = b2f_raw(q[3]);
  return r;
}
__device__ __forceinline__ void st4(float* p, f4 v) { *(f4*)p = v; }
__device__ __forceinline__ void st4(u16* p, f4 v) {
  u16x4 q;
  q[0] = f2b_raw(v[0]); q[1] = f2b_raw(v[1]);
  q[2] = f2b_raw(v[2]); q[3] = f2b_raw(v[3]);
  *(u16x4*)p = q;
}

__device__ __forceinline__ bf16x8 cvt_bf8(f4 a, f4 b) {
  bf16x8 r;
#pragma unroll
  for (int e = 0; e < 4; ++e) {
    r[e] = (short)f2b_raw(a[e]);
    r[4 + e] = (short)f2b_raw(b[e]);
  }
  return r;
}

// byte-address swizzle for 256B-row i8 LDS tiles (row bits 8-10 -> slot bits 4-6)
__device__ __forceinline__ int swz8(int byte) {
  return byte ^ (((byte >> 8) & 7) << 4);
}

// LDS-only barrier: order ds ops, let vmem (y stores, zx loads) fly across.
__device__ __forceinline__ void lds_barrier() {
  asm volatile("s_waitcnt lgkmcnt(0)" ::: "memory");
  __builtin_amdgcn_s_barrier();
}

// ---------------------------------------------------------------------------
__global__ void fill_val(float* o, float v, unsigned n) {
  unsigned i = blockIdx.x * 256u + threadIdx.x;
  if (i < n) o[i] = v;
}

// f32 -> raw-bf16 elementwise convert (for W_ih); n multiple of 1024.
__global__ __launch_bounds__(256) void cvt_bf16(const float* __restrict__ src,
                                                u16* __restrict__ dst,
                                                unsigned n) {
  unsigned i = (blockIdx.x * 256u + threadIdx.x) * 4u;
  if (i + 3 < n) {
    f4 v = *(const f4*)(src + i);
    st4(dst + i, v);
  }
}

// Per-column int8 quantization of W_hh: wq[col][k], wsc[col] = s/(127*127).
__global__ __launch_bounds__(256) void cvt_w_i8(const float* __restrict__ src,
                                                signed char* __restrict__ wq,
                                                float* __restrict__ wsc) {
  const int col = blockIdx.x * 4 + (threadIdx.x >> 6);
  const int lane = threadIdx.x & 63;
  const float* sp = src + (size_t)col * 256 + lane * 4;
  f4 v = *(const f4*)sp;
  float m = fmaxf(fmaxf(fabsf(v[0]), fabsf(v[1])),
                  fmaxf(fabsf(v[2]), fabsf(v[3])));
#pragma unroll
  for (int off = 32; off; off >>= 1) m = fmaxf(m, __shfl_xor(m, off));
  m = fmaxf(m, 1e-20f);
  const float r = 127.0f / m;
  signed char qb[4];
#pragma unroll
  for (int e = 0; e < 4; ++e) qb[e] = (signed char)__float2int_rn(v[e] * r);
  *(int*)(wq + (size_t)col * 256 + lane * 4) = *(int*)qb;
  if (lane == 0) wsc[col] = m / (127.0f * 127.0f);
}

// ---------------------------------------------------------------------------
// bf16 MFMA zx-GEMM body. Block gb covers a 64x256 tile of one dir's
// [CT*64 x 1024] zx chunk. 16 waves: wave w -> rows (w&3)*16, cols (w>>2)*64.
// B operand from pre-converted bf16 wihb (direct loads, no in-reg cvt).
// Writes dense zx layout ((dd*CT+t)*4+bg)*16384 + col*16 + bi.
// ---------------------------------------------------------------------------
template <int CT, int LAYER>
__device__ __forceinline__ void zx_gemm_body(
    int gb, int tid, u16* __restrict__ zx_nxt, const float* __restrict__ xsrc,
    const u16* __restrict__ ysrc, const u16* __restrict__ wihb,
    const float* __restrict__ bih, const float* __restrict__ bhh, int t0dF,
    int t0dR) {
  const int dd = gb / (4 * CT);
  const int rr = gb % (4 * CT);
  const int mblk = rr >> 2;  // t-step within chunk
  const int nblk = rr & 3;   // 256-col group
  const int w = tid >> 6, l = tid & 63;
  const int c = l & 15, q = l >> 4;
  const int mt = w & 3;      // 16-row tile (= bg)
  const int ct4 = w >> 2;    // 64-col strip
  const int K = LAYER ? 512 : 128;
  const int tg = (dd ? t0dR : t0dF) + mblk;
  const int bb = mt * 16 + c;  // A row (batch within 64)
  const int n0 = nblk * 256 + ct4 * 64;

  const u16* wB = wihb + (size_t)dd * 1024 * K;

  f32x4 acc[4];
#pragma unroll
  for (int j = 0; j < 4; ++j) acc[j] = (f32x4){0.f, 0.f, 0.f, 0.f};

  for (int k0 = 0; k0 < K; k0 += 32) {
    bf16x8 afrag;
    if (LAYER == 0) {
      const float* ap =
          xsrc + (size_t)bb * (1024 * 128) + (size_t)tg * 128 + k0 + q * 8;
      afrag = cvt_bf8(*(const f4*)ap, *(const f4*)(ap + 4));
    } else {
      afrag =
          *(const bf16x8*)(ysrc + ((size_t)tg * 64 + bb) * 512 + k0 + q * 8);
    }
#pragma unroll
    for (int j = 0; j < 4; ++j) {
      const int col = n0 + j * 16 + c;
      bf16x8 bfrag = *(const bf16x8*)(wB + (size_t)col * K + k0 + q * 8);
      acc[j] = __builtin_amdgcn_mfma_f32_16x16x32_bf16(afrag, bfrag, acc[j],
                                                       0, 0, 0);
    }
  }
  // D row=q*4+i -> b = mt*16 + q*4+i -> bg=mt, bi=q*4+i (u16x4 store)
  u16* base = zx_nxt + ((size_t)(dd * CT + mblk) * 4 + mt) * 16384;
#pragma unroll
  for (int j = 0; j < 4; ++j) {
    const int col = n0 + j * 16 + c;
    const float bvv = bih[dd * 1024 + col] + bhh[dd * 1024 + col];
    u16x4 o;
#pragma unroll
    for (int i = 0; i < 4; ++i) o[i] = f2b_raw(acc[j][i] + bvv);
    *(u16x4*)(base + (size_t)col * 16 + q * 4) = o;
  }
}

// Standalone prologue version.
template <int CT, int LAYER>
__global__ __launch_bounds__(1024) void gemm_zx(
    u16* __restrict__ zx_dst, const float* __restrict__ xsrc,
    const u16* __restrict__ ysrc, const u16* __restrict__ wihb,
    const float* __restrict__ bih, const float* __restrict__ bhh, int t0dF,
    int t0dR) {
  zx_gemm_body<CT, LAYER>(blockIdx.x, threadIdx.x, zx_dst, xsrc, ysrc, wihb,
                          bih, bhh, t0dF, t0dR);
}

// ---------------------------------------------------------------------------
// Head GEMM (f32): out = y1 @ lin_w^T + b.
// ---------------------------------------------------------------------------
__global__ __launch_bounds__(256) void gemm_head(
    const u16* __restrict__ A, const float* __restrict__ Bw,
    const float* __restrict__ bias1, float* __restrict__ C, int K, int N) {
  const int tid = threadIdx.x;
  const int nt = blockIdx.x, mt = blockIdx.y;
  const int tx = tid & 15, ty = tid >> 4;

  __shared__ float As[32 * 64];
  __shared__ float Bs[32 * 64];

  f4 zero = {0.f, 0.f, 0.f, 0.f};
  f4 acc[4] = {zero, zero, zero, zero};

  const int am = tid & 63, akq = tid >> 6;
  const long abase = (long)am * K + (long)mt * 64 * K;

  for (int kt = 0; kt < K; kt += 32) {
    {
      const u16* ap = A + abase + kt + akq * 8;
      f4 v0 = ld4(ap);
      f4 v1 = ld4(ap + 4);
#pragma unroll
      for (int e = 0; e < 4; ++e) {
        As[(akq * 8 + e) * 64 + am] = v0[e];
        As[(akq * 8 + 4 + e) * 64 + am] = v1[e];
      }
      const float* bp = Bw + (size_t)((nt * 64 + am) & 63) * K + kt + akq * 8;
      f4 w0 = *(const f4*)bp;
      f4 w1 = *(const f4*)(bp + 4);
#pragma unroll
      for (int e = 0; e < 4; ++e) {
        Bs[(akq * 8 + e) * 64 + am] = w0[e];
        Bs[(akq * 8 + 4 + e) * 64 + am] = w1[e];
      }
    }
    __syncthreads();
#pragma unroll 8
    for (int k = 0; k < 32; ++k) {
      f4 a = *(const f4*)(As + k * 64 + ty * 4);
      f4 b = *(const f4*)(Bs + k * 64 + tx * 4);
      acc[0] += b * a[0];
      acc[1] += b * a[1];
      acc[2] += b * a[2];
      acc[3] += b * a[3];
    }
    __syncthreads();
  }
  f4 bv = *(const f4*)(bias1 + nt * 64 + tx * 4);
  float* Cp = C + ((size_t)mt * 64 + ty * 4) * N + nt * 64 + tx * 4;
#pragma unroll
  for (int i = 0; i < 4; ++i) st4(Cp + (size_t)i * N, acc[i] + bv);
}

// ---------------------------------------------------------------------------
// Fused kernel: blocks 0-7 = int8 MFMA recurrence (prio 1); blocks 8.. =
// bf16 MFMA zx GEMM for NEXT chunk (prio 0, fills idle slots).
// ---------------------------------------------------------------------------
template <int CT, int LAYER>
__global__ __launch_bounds__(1024) void rec_fused(
    const u16* __restrict__ zx_cur, u16* __restrict__ zx_nxt,
    const float* __restrict__ xsrc, const u16* __restrict__ ysrc,
    const u16* __restrict__ wihb, const float* __restrict__ bih,
    const float* __restrict__ bhh, const signed char* __restrict__ wq,
    const float* __restrict__ wsc, const float* __restrict__ h0,
    const float* __restrict__ c0, int l2, float* __restrict__ cstate,
    u16* __restrict__ y, int t0, int t0dF, int t0dR, int do_gemm) {
  __shared__ alignas(16) char hls[2 * 4096];
  __shared__ float sred[8];

  const int tid = threadIdx.x;

  if (blockIdx.x >= 8) {
    if (!do_gemm) return;
    zx_gemm_body<CT, LAYER>((int)blockIdx.x - 8, tid, zx_nxt, xsrc, ysrc,
                            wihb, bih, bhh, t0dF, t0dR);
    return;
  }

  // ================= REC part (blocks 0-7) =================
  __builtin_amdgcn_s_setprio(1);  // favor rec waves over co-resident gemm

  const int w = tid >> 6, l = tid & 63;
  const int c = l & 15, q = l >> 4;
  const int d = blockIdx.x >> 2, bg = blockIdx.x & 3;
  const int u0 = w * 16, b0 = bg * 16;
  const int sidx = l2 + d;

  // resident W_hh fragments + scales (64 VGPR)
  i32x4 wf[4][4];
  float sc[4];
  {
    const signed char* wd = wq + (size_t)d * 1024 * 256;
#pragma unroll
    for (int g = 0; g < 4; ++g) {
      const int col = g * 256 + u0 + c;
      sc[g] = wsc[d * 1024 + col];
#pragma unroll
      for (int kt = 0; kt < 4; ++kt)
        wf[kt][g] = *(const i32x4*)(wd + (size_t)col * 256 + kt * 64 + q * 16);
    }
  }

  // h init (first 512 threads; barrier hoisted)
  float hv8[8];
  const int hb = tid >> 5, hg = tid & 31;
  if (tid < 512) {
    if (t0 == 0) {
      const float* hp = h0 + ((size_t)sidx * 64 + b0 + hb) * 256 + hg * 8;
      f4 v0 = ld4(hp), v1 = ld4(hp + 4);
#pragma unroll
      for (int e = 0; e < 4; ++e) { hv8[e] = v0[e]; hv8[4 + e] = v1[e]; }
    } else {
      const int r0 = d ? (S_LEN - t0) : (t0 - 1);
      const u16* hp = y + ((size_t)r0 * 64 + b0 + hb) * 512 + d * 256 + hg * 8;
      f4 v0 = ld4(hp), v1 = ld4(hp + 4);
#pragma unroll
      for (int e = 0; e < 4; ++e) { hv8[e] = v0[e]; hv8[4 + e] = v1[e]; }
    }
    float m = 0.f;
#pragma unroll
    for (int e = 0; e < 8; ++e) m = fmaxf(m, fabsf(hv8[e]));
#pragma unroll
    for (int off = 32; off; off >>= 1) m = fmaxf(m, __shfl_xor(m, off));
    if (l == 0) sred[w] = m;
  }
  __syncthreads();
  float s_h0;
  {
    float m = 1e-20f;
#pragma unroll
    for (int i = 0; i < 8; ++i) m = fmaxf(m, sred[i]);
    s_h0 = m;
  }
  if (tid < 512) {
    const float r = 127.0f / s_h0;
#pragma unroll
    for (int e = 0; e < 8; ++e) {
      hls[swz8(hb * 256 + hg * 8 + e)] =
          (signed char)__float2int_rn(hv8[e] * r);
    }
  }

  // c state
  float cst[4];
  if (t0 == 0) {
#pragma unroll
    for (int i = 0; i < 4; ++i)
      cst[i] = c0[((size_t)sidx * 64 + b0 + q * 4 + i) * 256 + u0 + c];
  } else {
    const float* cp = cstate + ((size_t)blockIdx.x * 1024 + tid) * 4;
#pragma unroll
    for (int i = 0; i < 4; ++i) cst[i] = cp[i];
  }
  __syncthreads();

  // incremental pointers (dense zx layout)
  const u16* zp =
      zx_cur + ((size_t)(d * CT + (d ? CT - 1 : 0)) * 4 + bg) * 16384;
  const long zstep = d ? -65536L : 65536L;
  int zo[4];
#pragma unroll
  for (int g = 0; g < 4; ++g) zo[g] = g * 4096 + (u0 + c) * 16 + q * 4;
  u16* yp = y + ((size_t)(d ? (S_LEN - 1 - t0) : t0) * 64 + b0) * 512 +
            d * 256 + u0 + c;
  const long ystep = d ? -32768L : 32768L;

  // first step's zq (in flight during h-init epilogue)
  u16x4 zq[4];
#pragma unroll
  for (int g = 0; g < 4; ++g) zq[g] = *(const u16x4*)(zp + zo[g]);

  float s_cur = s_h0;
  for (int tl = 0; tl < CT; ++tl) {
    const int curo = (tl & 1) * 4096, nxto = 4096 - curo;

    // issue NEXT step's zx loads; they stay in flight across the raw barrier.
    const u16* zpn = zp + zstep;
    u16x4 zqn[4];
#pragma unroll
    for (int g = 0; g < 4; ++g) zqn[g] = *(const u16x4*)(zpn + zo[g]);

    // h @ W_hh^T : 4 k-tiles (K=64) x 4 gate-tiles, B resident
    i32x4 acc[4];
#pragma unroll
    for (int g = 0; g < 4; ++g) acc[g] = (i32x4){0, 0, 0, 0};
#pragma unroll
    for (int kt = 0; kt < 4; ++kt) {
      i32x4 af = *(const i32x4*)(hls + curo + swz8(c * 256 + kt * 64 + q * 16));
#pragma unroll
      for (int g = 0; g < 4; ++g)
        acc[g] = __builtin_amdgcn_mfma_i32_16x16x64_i8(af, wf[kt][g],
                                                       acc[g], 0, 0, 0);
    }

    // gates + state update: 4 outputs/lane (b=q*4+i, u=u0+c)
    const float sI = sc[0] * s_cur, sF = sc[1] * s_cur;
    const float sG = sc[2] * s_cur, sO = sc[3] * s_cur;
#pragma unroll
    for (int i = 0; i < 4; ++i) {
      const float zI = b2f_raw(zq[0][i]) + sI * (float)acc[0][i];
      const float zF = b2f_raw(zq[1][i]) + sF * (float)acc[1][i];
      const float zG = b2f_raw(zq[2][i]) + sG * (float)acc[2][i];
      const float zO = b2f_raw(zq[3][i]) + sO * (float)acc[3][i];
      const float cv = fsig(zF) * cst[i] + fsig(zI) * ftanh(zG);
      cst[i] = cv;
      const float hv = fsig(zO) * ftanh(cv);
      const int b = q * 4 + i;
      hls[nxto + swz8(b * 256 + u0 + c)] =
          (signed char)__float2int_rn(hv * 127.0f);
      yp[(size_t)b * 512] = f2b_raw(hv);
    }
    s_cur = 1.0f;
#pragma unroll
    for (int g = 0; g < 4; ++g) zq[g] = zqn[g];
    zp = zpn;
    yp += ystep;
    lds_barrier();
  }

  __builtin_amdgcn_s_setprio(0);
  {
    float* cp = cstate + ((size_t)blockIdx.x * 1024 + tid) * 4;
#pragma unroll
    for (int i = 0; i < 4; ++i) cp[i] = cst[i];
  }
}

// ---------------------------------------------------------------------------
struct Args {
  const float *x, *h0, *c0, *wih0, *whh0, *bih0, *bhh0, *wih1, *whh1, *bih1,
      *bhh1, *linw, *linb;
  float* out;
  u16 *y0, *y1, *zxA, *zxB, *wihb;
  signed char* wq;
  float *wsc, *cstate;
};

template <int CTT>
static void run_pipeline(const Args& a, hipStream_t stream) {
  const int nC = S_LEN / CTT;
  const int NG = 8 * CTT;
  for (int L = 0; L < 2; ++L) {
    const unsigned nWI = L ? (2u * 1024u * 512u) : (2u * 1024u * 128u);
    cvt_w_i8<<<dim3(512), 256, 0, stream>>>(L ? a.whh1 : a.whh0, a.wq, a.wsc);
    cvt_bf16<<<dim3(nWI / 1024u), 256, 0, stream>>>(L ? a.wih1 : a.wih0,
                                                    a.wihb, nWI);
    // chunk-0 prologue gemm (both dirs inside one launch) -> zxA
    if (L == 0) {
      gemm_zx<CTT, 0><<<dim3(NG), 1024, 0, stream>>>(
          a.zxA, a.x, nullptr, a.wihb, a.bih0, a.bhh0, 0, S_LEN - CTT);
    } else {
      gemm_zx<CTT, 1><<<dim3(NG), 1024, 0, stream>>>(
          a.zxA, nullptr, a.y0, a.wihb, a.bih1, a.bhh1, 0, S_LEN - CTT);
    }
    u16* yl = L ? a.y1 : a.y0;
    for (int ch = 0; ch < nC; ++ch) {
      u16* zc = (ch & 1) ? a.zxB : a.zxA;
      u16* zn = (ch & 1) ? a.zxA : a.zxB;
      const int t0dF = (ch + 1) * CTT;
      const int t0dR = S_LEN - (ch + 2) * CTT;
      const int dg = (ch + 1 < nC) ? 1 : 0;
      if (L == 0) {
        rec_fused<CTT, 0><<<dim3(8 + NG), 1024, 0, stream>>>(
            zc, zn, a.x, nullptr, a.wihb, a.bih0, a.bhh0, a.wq, a.wsc, a.h0,
            a.c0, 0, a.cstate, yl, ch * CTT, t0dF, t0dR, dg);
      } else {
        rec_fused<CTT, 1><<<dim3(8 + NG), 1024, 0, stream>>>(
            zc, zn, nullptr, a.y0, a.wihb, a.bih1, a.bhh1, a.wq, a.wsc, a.h0,
            a.c0, 2, a.cstate, yl, ch * CTT, t0dF, t0dR, dg);
      }
    }
  }
  // head: out = y1 @ lin_w^T + lin_b
  gemm_head<<<dim3(1, 1024, 1), 256, 0, stream>>>(a.y1, a.linw, a.linb, a.out,
                                                  512, 64);
}

// ---------------------------------------------------------------------------
extern "C" void kernel_launch(void* const* d_in, const int* in_sizes, int n_in,
                              void* d_out, int out_size, void* d_ws,
                              size_t ws_size, hipStream_t stream) {
  Args a;
  a.x    = (const float*)d_in[0];
  a.h0   = (const float*)d_in[1];
  a.c0   = (const float*)d_in[2];
  a.wih0 = (const float*)d_in[3];
  a.whh0 = (const float*)d_in[4];
  a.bih0 = (const float*)d_in[5];
  a.bhh0 = (const float*)d_in[6];
  a.wih1 = (const float*)d_in[7];
  a.whh1 = (const float*)d_in[8];
  a.bih1 = (const float*)d_in[9];
  a.bhh1 = (const float*)d_in[10];
  a.linw = (const float*)d_in[11];
  a.linb = (const float*)d_in[12];
  a.out  = (float*)d_out;

  const size_t Yb  = (size_t)S_LEN * 64 * 512 * 2;  // 64 MB each
  const size_t WQb = 2UL * 1024 * 256;              // 512 KB
  const size_t WSb = 2UL * 1024 * 4;                // 8 KB
  const size_t WIb = 2UL * 1024 * 512 * 2;          // 2 MB (bf16 W_ih, max K)
  const size_t CSb = 8UL * 1024 * 4 * 4;            // 128 KB
  const size_t fixed = 2 * Yb + WQb + WSb + WIb + CSb;

  int CT = 0;
  const int cands[6] = {256, 128, 64, 32, 16, 8};
  for (int ci = 0; ci < 6; ++ci) {
    const size_t zxb = (size_t)cands[ci] * 262144;  // bytes per buffer
    if (fixed + 2 * zxb <= ws_size) { CT = cands[ci]; break; }
  }
  if (CT == 0) {  // diagnostic: absmax == ws MB
    fill_val<<<dim3(((unsigned)out_size + 255u) / 256u), 256, 0, stream>>>(
        a.out, (float)(unsigned)(ws_size >> 20), (unsigned)out_size);
    return;
  }

  char* wsp = (char*)d_ws;
  a.y0     = (u16*)wsp;
  a.y1     = (u16*)(wsp + Yb);
  a.wq     = (signed char*)(wsp + 2 * Yb);
  a.wsc    = (float*)(wsp + 2 * Yb + WQb);
  a.wihb   = (u16*)(wsp + 2 * Yb + WQb + WSb);
  a.cstate = (float*)(wsp + 2 * Yb + WQb + WSb + WIb);
  a.zxA    = (u16*)(wsp + fixed);
  a.zxB    = (u16*)(wsp + fixed + (size_t)CT * 262144);

  switch (CT) {
    case 256: run_pipeline<256>(a, stream); break;
    case 128: run_pipeline<128>(a, stream); break;
    case 64:  run_pipeline<64>(a, stream); break;
    case 32:  run_pipeline<32>(a, stream); break;
    case 16:  run_pipeline<16>(a, stream); break;
    default:  run_pipeline<8>(a, stream); break;
  }
}